// Round 7
// baseline (233.151 us; speedup 1.0000x reference)
//
#include <hip/hip_runtime.h>
#include <hip/hip_bf16.h>

#define T_SEQ 2048
#define D_MODEL 1024
#define N_HEADS 16

typedef _Float16 half8 __attribute__((ext_vector_type(8)));
typedef _Float16 half4 __attribute__((ext_vector_type(4)));
typedef _Float16 half2v __attribute__((ext_vector_type(2)));
typedef float floatx4 __attribute__((ext_vector_type(4)));
typedef float floatx16 __attribute__((ext_vector_type(16)));
typedef unsigned short ushort4v __attribute__((ext_vector_type(4)));
typedef unsigned short ushort8v __attribute__((ext_vector_type(8)));
typedef unsigned int uintx4 __attribute__((ext_vector_type(4)));

#define LOG2E 1.44269504088896f

__device__ __forceinline__ unsigned short f32_to_bf16(float f) {
  unsigned u = __builtin_bit_cast(unsigned, f);
  u = u + 0x7FFFu + ((u >> 16) & 1u);
  return (unsigned short)(u >> 16);
}
__device__ __forceinline__ float bf16_to_f32(unsigned short h) {
  unsigned u = ((unsigned)h) << 16;
  return __builtin_bit_cast(float, u);
}
__device__ __forceinline__ half2v pk_f16(float a, float b) {
  return __builtin_bit_cast(half2v, __builtin_amdgcn_cvt_pkrtz(a, b));
}

// async 16B/lane global->LDS. lds base must be wave-uniform; HW adds lane*16.
__device__ __forceinline__ void load16_lds(const _Float16* g, _Float16* lds_base, int lane) {
#if __has_builtin(__builtin_amdgcn_global_load_lds)
  __builtin_amdgcn_global_load_lds(
      (const __attribute__((address_space(1))) void*)g,
      (__attribute__((address_space(3))) void*)lds_base, 16, 0, 0);
#else
  *(half8*)(lds_base + lane * 8) = *(const half8*)g;
#endif
}

// ---------------- dtype detection (bf16 vs fp32 inputs) ----------------
__global__ void k_detect(const unsigned short* __restrict__ x, int* __restrict__ flag) {
  __shared__ int cnt;
  if (threadIdx.x == 0) cnt = 0;
  __syncthreads();
  unsigned short v = x[(size_t)threadIdx.x * 2];
  int e = (v >> 7) & 0xFF;
  int ok = (v == 0) || (e >= 100 && e <= 150);
  atomicAdd(&cnt, ok);
  __syncthreads();
  if (threadIdx.x == 0) *flag = (cnt >= 192) ? 1 : 0;  // 1 = bf16 inputs
}

// ---------------- conversions ----------------
// 8 elements/thread, vectorized both paths
__global__ void k_cvt_h8(const void* __restrict__ in, _Float16* __restrict__ out,
                         int n8, const int* __restrict__ flag) {
  int f = *flag;
  int i = blockIdx.x * 256 + threadIdx.x;
  if (i >= n8) return;
  half8 o;
  if (f) {
    ushort8v u = ((const ushort8v*)in)[i];
#pragma unroll
    for (int e = 0; e < 8; ++e) o[e] = (_Float16)bf16_to_f32(u[e]);
  } else {
    floatx4 a = ((const floatx4*)in)[2 * i];
    floatx4 b = ((const floatx4*)in)[2 * i + 1];
#pragma unroll
    for (int e = 0; e < 4; ++e) { o[e] = (_Float16)a[e]; o[e + 4] = (_Float16)b[e]; }
  }
  ((half8*)out)[i] = o;
}

// biases + mask (mask pre-scaled by 2*log2e for exp2-domain softmax)
__global__ void k_cvt3(const void* __restrict__ ba, const void* __restrict__ bp,
                       const void* __restrict__ mk, float* __restrict__ baF,
                       float* __restrict__ bpF, float* __restrict__ mask2,
                       const int* __restrict__ flag) {
  int f = *flag;
  int i = blockIdx.x * 256 + threadIdx.x;
  auto cv = [&](const void* p, int j) {
    return f ? bf16_to_f32(((const unsigned short*)p)[j]) : ((const float*)p)[j];
  };
  if (i < 3072) baF[i] = cv(ba, i);
  else if (i < 4096) bpF[i - 3072] = cv(bp, i - 3072);
  else mask2[i - 4096] = cv(mk, i - 4096) * (2.0f * LOG2E);
}

// out[n*K + k] = (fp16) in[k*N + n]; two weights in one launch
__global__ __launch_bounds__(256) void k_transpose2(
    const void* __restrict__ inA, _Float16* __restrict__ outA,
    const void* __restrict__ inB, _Float16* __restrict__ outB,
    const int* __restrict__ flag) {
  __shared__ float tile[32][33];
  int f = *flag;
  const void* in;
  _Float16* out;
  int N, bid;
  if (blockIdx.x < 3072) { in = inA; out = outA; N = 3072; bid = blockIdx.x; }
  else { in = inB; out = outB; N = 1024; bid = blockIdx.x - 3072; }
  const int K = 1024;
  int nb = N >> 5;
  int bx = bid % nb, by = bid / nb;
  int n0 = bx << 5, k0 = by << 5;
  int c = threadIdx.x & 31, r = threadIdx.x >> 5;
  const float* fin = (const float*)in;
  const unsigned short* uin = (const unsigned short*)in;
#pragma unroll
  for (int i = 0; i < 4; ++i) {
    int kk = r + i * 8;
    size_t idx = (size_t)(k0 + kk) * N + n0 + c;
    tile[kk][c] = f ? bf16_to_f32(uin[idx]) : fin[idx];
  }
  __syncthreads();
#pragma unroll
  for (int i = 0; i < 4; ++i) {
    int nn = r + i * 8;
    out[(size_t)(n0 + nn) * K + k0 + c] = (_Float16)tile[c][nn];
  }
}

// ---------------- GEMM: D[m][n] = sum_k A[m][k]*BT[n][k] + bias[m] ----------------
template <int TM>
__global__ __launch_bounds__(256) void k_gemm(
    const _Float16* __restrict__ A, const _Float16* __restrict__ BT,
    const float* __restrict__ bias, void* __restrict__ D0,
    void* __restrict__ D1, void* __restrict__ D2,
    int M, int N, int K, int outKind, const int* __restrict__ flag) {
  constexpr int IM = TM / 32;  // acc tiles per wave in M
  __shared__ _Float16 As[TM * 32] __attribute__((aligned(16)));
  __shared__ _Float16 Bs[128 * 32] __attribute__((aligned(16)));
  const int tid = threadIdx.x;
  const int wave = tid >> 6, lane = tid & 63;
  const int ln = lane & 15, quad = lane >> 4;
  const int bm = blockIdx.y * TM, bn = blockIdx.x * 128;
  const int wm = (wave & 1) * (TM / 2), wn = (wave >> 1) * 64;

  const int r0 = tid >> 2, k0 = (tid & 3) * 8;
  const int r1 = (tid + 256) >> 2, k1 = (tid & 3) * 8;
  _Float16* As0 = As + (size_t)(wave * 64) * 8;
  _Float16* As1 = As + (size_t)(wave * 64 + 256) * 8;
  _Float16* Bs0 = Bs + (size_t)(wave * 64) * 8;
  _Float16* Bs1 = Bs + (size_t)(wave * 64 + 256) * 8;
  const _Float16* Ag0 = A + (size_t)(bm + r0) * K + k0;
  const _Float16* Ag1 = A + (size_t)(bm + r1) * K + k1;
  const _Float16* Bg0 = BT + (size_t)(bn + r0) * K + k0;
  const _Float16* Bg1 = BT + (size_t)(bn + r1) * K + k1;

  floatx4 acc[IM][4] = {};

  for (int kt = 0; kt < K; kt += 32) {
    __syncthreads();
    load16_lds(Ag0 + kt, As0, lane);
    if constexpr (TM == 128) load16_lds(Ag1 + kt, As1, lane);
    load16_lds(Bg0 + kt, Bs0, lane);
    load16_lds(Bg1 + kt, Bs1, lane);
    __syncthreads();
    half8 af[IM], bf[4];
#pragma unroll
    for (int i = 0; i < IM; ++i)
      af[i] = *(const half8*)(As + (wm + i * 16 + ln) * 32 + quad * 8);
#pragma unroll
    for (int j = 0; j < 4; ++j)
      bf[j] = *(const half8*)(Bs + (wn + j * 16 + ln) * 32 + quad * 8);
#pragma unroll
    for (int i = 0; i < IM; ++i)
#pragma unroll
      for (int j = 0; j < 4; ++j)
        acc[i][j] = __builtin_amdgcn_mfma_f32_16x16x32_f16(af[i], bf[j], acc[i][j], 0, 0, 0);
  }

  if (outKind == 0) {
    _Float16* Qs = (_Float16*)D0;
    _Float16* Ks = (_Float16*)D1;
    _Float16* Vt = (_Float16*)D2;
    const float qsc = 0.125f * LOG2E;  // 1/sqrt(64) and log2e folded into Q
#pragma unroll
    for (int i = 0; i < IM; ++i) {
      int rbase = bm + wm + i * 16 + quad * 4;  // qkv feature, 4-aligned
      int sect = rbase >> 10;                   // 0:Q 1:K 2:V (wave-uniform)
      int cfeat = rbase & 1023;
      int h = cfeat >> 6, hd = cfeat & 63;
      float bv[4];
#pragma unroll
      for (int r = 0; r < 4; ++r) bv[r] = bias[rbase + r];
#pragma unroll
      for (int j = 0; j < 4; ++j) {
        int col = bn + wn + j * 16 + ln;        // global token
        int b = col >> 11, t = col & 2047;
        size_t bh = (size_t)b * N_HEADS + h;
        float v[4];
#pragma unroll
        for (int r = 0; r < 4; ++r) v[r] = acc[i][j][r] + bv[r];
        if (sect == 0) {
          half4 q;
#pragma unroll
          for (int r = 0; r < 4; ++r) q[r] = (_Float16)(v[r] * qsc);
          *(half4*)(Qs + (bh * T_SEQ + t) * 64 + hd) = q;
        } else if (sect == 1) {
          half4 kk4;
#pragma unroll
          for (int r = 0; r < 4; ++r) kk4[r] = (_Float16)v[r];
          *(half4*)(Ks + (bh * T_SEQ + t) * 64 + hd) = kk4;
        } else {
#pragma unroll
          for (int r = 0; r < 4; ++r)
            Vt[(bh * 64 + hd + r) * T_SEQ + t] = (_Float16)v[r];
        }
      }
    }
  } else {
    int mode = (*flag) ? 2 : 1;  // 2: bf16 out, 1: fp32 out
#pragma unroll
    for (int i = 0; i < IM; ++i) {
      int rbase = bm + wm + i * 16 + quad * 4;
      float bv[4];
#pragma unroll
      for (int r = 0; r < 4; ++r) bv[r] = bias[rbase + r];
#pragma unroll
      for (int j = 0; j < 4; ++j) {
        int col = bn + wn + j * 16 + ln;
        float v[4];
#pragma unroll
        for (int r = 0; r < 4; ++r) v[r] = acc[i][j][r] + bv[r];
        if (mode == 1) {
          floatx4 o = {v[0], v[1], v[2], v[3]};
          *(floatx4*)((float*)D0 + (size_t)col * M + rbase) = o;
        } else {
          ushort4v o;
#pragma unroll
          for (int r = 0; r < 4; ++r) o[r] = f32_to_bf16(v[r]);
          *(ushort4v*)((unsigned short*)D0 + (size_t)col * M + rbase) = o;
        }
      }
    }
  }
}

// ---------------- flash attention: 32x32 MFMA, 32 queries/wave ----------------
// block = (b, h, 128 queries) = 4 waves x 32 q; 64-key tiles, dbuf K/V (32 KB).
// S^T[key][q] = K.Q^T via mfma_32x32x16(kf, qf): C col = q = lane&31,
// row = key = (reg&3)+8*(reg>>2)+4*(lane>>5)  [m74/m101 layout].
// A/B frags: [dim = lane&31][k = (lane>>5)*8 + e].
// P (C-layout) -> PV B-operand via ONE __shfl_xor(.,32) register exchange per
// 16-key fragment -- no LDS round-trip. O^T = V^T.P^T accumulated in C-layout.
// Fixed-reference softmax (tile-0 max), exp2-domain, mask as MFMA C-init.
__global__ __launch_bounds__(256) void k_flash(
    const _Float16* __restrict__ Qs, const _Float16* __restrict__ Ks,
    const _Float16* __restrict__ Vt, const float* __restrict__ mask2,
    _Float16* __restrict__ O) {
  __shared__ _Float16 Kl[2][64 * 64] __attribute__((aligned(16)));  // [key][d] swizzled
  __shared__ _Float16 Vl[2][64 * 64] __attribute__((aligned(16)));  // [d][key] swizzled
  const int tid = threadIdx.x, wave = tid >> 6, lane = tid & 63;
  const int l31 = lane & 31, h5 = lane >> 5, swz = l31 & 7;
  const int id = blockIdx.x;
  const int qc = id & 15, hh = (id >> 4) & 15, b = id >> 8;  // grid 512
  const size_t bh = (size_t)b * N_HEADS + hh;
  const _Float16* Qb = Qs + bh * T_SEQ * 64;
  const _Float16* Kb = Ks + bh * T_SEQ * 64;
  const _Float16* Vb = Vt + bh * 64 * T_SEQ;
  const int q0 = qc * 128 + wave * 32;  // wave's query base

  // Q B-frags: qf[ks] = Q[q=q0+l31][d = ks*16 + h5*8 + e]
  half8 qf[4];
#pragma unroll
  for (int ks = 0; ks < 4; ++ks)
    qf[ks] = *(const half8*)(Qb + (size_t)(q0 + l31) * 64 + ks * 16 + h5 * 8);

  floatx16 Oacc[2] = {};  // O^T: dg*32 + rowpat(reg,h5) x q=l31
  float m0 = 0.f, l_i = 0.f;

  // staging pointers, advanced by constants each tile
  const int sr = tid >> 3, scn = (tid & 7) ^ (sr & 7);
  const _Float16* kp0 = Kb + (size_t)sr * 64 + scn * 8;
  const _Float16* kp1 = kp0 + 32 * 64;
  const _Float16* vp0 = Vb + (size_t)sr * T_SEQ + scn * 8;
  const _Float16* vp1 = vp0 + 32 * T_SEQ;
  const float* mq = mask2 + (size_t)b * T_SEQ;  // key-indexed mask (2*log2e)

  // prime buffer 0
  {
    _Float16* K0 = &Kl[0][0] + (size_t)wave * 512;
    _Float16* V0 = &Vl[0][0] + (size_t)wave * 512;
    load16_lds(kp0, K0, lane);
    load16_lds(kp1, K0 + 2048, lane);
    load16_lds(vp0, V0, lane);
    load16_lds(vp1, V0 + 2048, lane);
    kp0 += 64 * 64; kp1 += 64 * 64; vp0 += 64; vp1 += 64;
  }

  for (int t = 0; t < 32; ++t) {
    const int cur = t & 1;
    __syncthreads();
    if (t + 1 < 32) {
      _Float16* K0 = &Kl[cur ^ 1][0] + (size_t)wave * 512;
      _Float16* V0 = &Vl[cur ^ 1][0] + (size_t)wave * 512;
      load16_lds(kp0, K0, lane);
      load16_lds(kp1, K0 + 2048, lane);
      load16_lds(vp0, V0, lane);
      load16_lds(vp1, V0 + 2048, lane);
      kp0 += 64 * 64; kp1 += 64 * 64; vp0 += 64; vp1 += 64;
    }
    const _Float16* Kc = &Kl[cur][0];
    const _Float16* Vc = &Vl[cur][0];

    // S^T for 2 key-groups of 32; mask as C-init (C row = key)
    floatx16 sa[2];
#pragma unroll
    for (int kg = 0; kg < 2; ++kg) {
      floatx16 z;
#pragma unroll
      for (int tt = 0; tt < 4; ++tt) {
        floatx4 mv = *(const floatx4*)(mq + kg * 32 + 8 * tt + 4 * h5);
#pragma unroll
        for (int i = 0; i < 4; ++i) z[4 * tt + i] = mv[i];
      }
#pragma unroll
      for (int ks = 0; ks < 4; ++ks) {
        half8 kf = *(const half8*)(Kc + (kg * 32 + l31) * 64 + ((ks * 2 + h5) ^ swz) * 8);
        z = __builtin_amdgcn_mfma_f32_32x32x16_f16(kf, qf[ks], z, 0, 0, 0);
      }
      sa[kg] = z;
    }
    mq += 64;

    if (t == 0) {
      float tmax = -__builtin_inff();
#pragma unroll
      for (int kg = 0; kg < 2; ++kg)
#pragma unroll
        for (int r = 0; r < 16; ++r) tmax = fmaxf(tmax, sa[kg][r]);
      tmax = fmaxf(tmax, __shfl_xor(tmax, 32, 64));
      m0 = fmaxf(tmax, -50.f);  // floor guards all-masked tile-0
    }

#pragma unroll
    for (int kg = 0; kg < 2; ++kg) {
#pragma unroll
      for (int r = 0; r < 16; ++r) {
        float p = __builtin_amdgcn_exp2f(sa[kg][r] - m0);
        sa[kg][r] = p;
        l_i += p;
      }
      // pack 4-key groups: regs 4t..4t+3 = keys kg*32 + 8t + 4*h5 + {0..3}
      unsigned pk[4][2];
#pragma unroll
      for (int tt = 0; tt < 4; ++tt) {
        half2v a = pk_f16(sa[kg][4 * tt], sa[kg][4 * tt + 1]);
        half2v bq = pk_f16(sa[kg][4 * tt + 2], sa[kg][4 * tt + 3]);
        pk[tt][0] = __builtin_bit_cast(unsigned, a);
        pk[tt][1] = __builtin_bit_cast(unsigned, bq);
      }
      // build PV B-frags (16 keys each) via one lane^32 exchange
#pragma unroll
      for (int ss = 0; ss < 2; ++ss) {
        int sendT = h5 ? 2 * ss : 2 * ss + 1;
        int ownT = h5 ? 2 * ss + 1 : 2 * ss;
        unsigned r0 = __shfl_xor(pk[sendT][0], 32, 64);
        unsigned r1 = __shfl_xor(pk[sendT][1], 32, 64);
        uintx4 u;
        if (h5 == 0) { u[0] = pk[ownT][0]; u[1] = pk[ownT][1]; u[2] = r0; u[3] = r1; }
        else         { u[0] = r0; u[1] = r1; u[2] = pk[ownT][0]; u[3] = pk[ownT][1]; }
        half8 pf = __builtin_bit_cast(half8, u);
        int kst = kg * 2 + ss;
#pragma unroll
        for (int dg = 0; dg < 2; ++dg) {
          half8 vf = *(const half8*)(Vc + (dg * 32 + l31) * 64 + ((kst * 2 + h5) ^ swz) * 8);
          Oacc[dg] = __builtin_amdgcn_mfma_f32_32x32x16_f16(vf, pf, Oacc[dg], 0, 0, 0);
        }
      }
    }
  }

  // lane-halves hold disjoint key sets of query l31
  l_i += __shfl_xor(l_i, 32, 64);
  float inv = 1.f / l_i;
  _Float16* Og = O + ((size_t)b * T_SEQ + q0 + l31) * D_MODEL + hh * 64;
#pragma unroll
  for (int dg = 0; dg < 2; ++dg)
#pragma unroll
    for (int tt = 0; tt < 4; ++tt) {
      half4 ov;
#pragma unroll
      for (int i = 0; i < 4; ++i) ov[i] = (_Float16)(Oacc[dg][4 * tt + i] * inv);
      *(half4*)(Og + dg * 32 + 8 * tt + 4 * h5) = ov;
    }
}

extern "C" void kernel_launch(void* const* d_in, const int* in_sizes, int n_in,
                              void* d_out, int out_size, void* d_ws, size_t ws_size,
                              hipStream_t stream) {
  const void* x      = d_in[0];
  const void* amask  = d_in[1];
  const void* w_attn = d_in[2];
  const void* b_attn = d_in[3];
  const void* w_proj = d_in[4];
  const void* b_proj = d_in[5];

  char* ws = (char*)d_ws;
  size_t off = 0;
  auto alloc = [&](size_t bytes) {
    void* p = ws + off;
    off += (bytes + 255) & ~(size_t)255;
    return p;
  };
  int* flag        = (int*)alloc(256);
  _Float16* Xh     = (_Float16*)alloc((size_t)4096 * 1024 * 2);
  _Float16* WaT    = (_Float16*)alloc((size_t)3072 * 1024 * 2);
  _Float16* WpT    = (_Float16*)alloc((size_t)1024 * 1024 * 2);
  float* baF       = (float*)alloc(3072 * 4);
  float* bpF       = (float*)alloc(1024 * 4);
  float* mask2     = (float*)alloc(4096 * 4);
  _Float16* Qs     = (_Float16*)alloc((size_t)4096 * 1024 * 2);
  _Float16* Ks     = (_Float16*)alloc((size_t)4096 * 1024 * 2);
  _Float16* Vt     = (_Float16*)alloc((size_t)4096 * 1024 * 2);
  _Float16* AttnH  = (_Float16*)alloc((size_t)4096 * 1024 * 2);

  k_detect<<<1, 256, 0, stream>>>((const unsigned short*)x, flag);
  k_cvt_h8<<<(4096 * 1024 / 8) / 256, 256, 0, stream>>>(x, Xh, 4096 * 1024 / 8, flag);
  k_transpose2<<<3072 + 1024, 256, 0, stream>>>(w_attn, WaT, w_proj, WpT, flag);
  k_cvt3<<<32, 256, 0, stream>>>(b_attn, b_proj, amask, baF, bpF, mask2, flag);

  // GEMM1: qkv^T = WaT(3072xK) . Xh(4096xK)^T, fused scatter to Qs/Ks/Vt
  dim3 g1(4096 / 128, 3072 / 128);
  k_gemm<128><<<g1, 256, 0, stream>>>(WaT, Xh, baF, Qs, Ks, Vt, 3072, 4096, 1024, 0, flag);

  k_flash<<<512, 256, 0, stream>>>(Qs, Ks, Vt, mask2, AttnH);

  // GEMM2: out^T = WpT(1024xK) . AttnH(4096xK)^T -> d_out [t][1024]
  dim3 g2(4096 / 128, 1024 / 128);
  k_gemm<128><<<g2, 256, 0, stream>>>(WpT, AttnH, bpF, d_out, nullptr, nullptr, 1024, 4096, 1024, 1, flag);
}

// Round 8
// 221.008 us; speedup vs baseline: 1.0549x; 1.0549x over previous
//
#include <hip/hip_runtime.h>
#include <hip/hip_bf16.h>

#define T_SEQ 2048
#define D_MODEL 1024
#define N_HEADS 16

typedef _Float16 half8 __attribute__((ext_vector_type(8)));
typedef _Float16 half4 __attribute__((ext_vector_type(4)));
typedef _Float16 half2v __attribute__((ext_vector_type(2)));
typedef float floatx4 __attribute__((ext_vector_type(4)));
typedef unsigned short ushort4v __attribute__((ext_vector_type(4)));
typedef unsigned short ushort8v __attribute__((ext_vector_type(8)));

#define LOG2E 1.44269504088896f

__device__ __forceinline__ unsigned short f32_to_bf16(float f) {
  unsigned u = __builtin_bit_cast(unsigned, f);
  u = u + 0x7FFFu + ((u >> 16) & 1u);
  return (unsigned short)(u >> 16);
}
__device__ __forceinline__ float bf16_to_f32(unsigned short h) {
  unsigned u = ((unsigned)h) << 16;
  return __builtin_bit_cast(float, u);
}
__device__ __forceinline__ half2v pk_f16(float a, float b) {
  return __builtin_bit_cast(half2v, __builtin_amdgcn_cvt_pkrtz(a, b));
}

// async 16B/lane global->LDS. lds base must be wave-uniform; HW adds lane*16.
__device__ __forceinline__ void load16_lds(const _Float16* g, _Float16* lds_base, int lane) {
#if __has_builtin(__builtin_amdgcn_global_load_lds)
  __builtin_amdgcn_global_load_lds(
      (const __attribute__((address_space(1))) void*)g,
      (__attribute__((address_space(3))) void*)lds_base, 16, 0, 0);
#else
  *(half8*)(lds_base + lane * 8) = *(const half8*)g;
#endif
}

// ---------------- dtype detection (bf16 vs fp32 inputs) ----------------
__global__ void k_detect(const unsigned short* __restrict__ x, int* __restrict__ flag) {
  __shared__ int cnt;
  if (threadIdx.x == 0) cnt = 0;
  __syncthreads();
  unsigned short v = x[(size_t)threadIdx.x * 2];
  int e = (v >> 7) & 0xFF;
  int ok = (v == 0) || (e >= 100 && e <= 150);
  atomicAdd(&cnt, ok);
  __syncthreads();
  if (threadIdx.x == 0) *flag = (cnt >= 192) ? 1 : 0;  // 1 = bf16 inputs
}

// ---------------- conversions ----------------
// 8 elements/thread, vectorized both paths
__global__ void k_cvt_h8(const void* __restrict__ in, _Float16* __restrict__ out,
                         int n8, const int* __restrict__ flag) {
  int f = *flag;
  int i = blockIdx.x * 256 + threadIdx.x;
  if (i >= n8) return;
  half8 o;
  if (f) {
    ushort8v u = ((const ushort8v*)in)[i];
#pragma unroll
    for (int e = 0; e < 8; ++e) o[e] = (_Float16)bf16_to_f32(u[e]);
  } else {
    floatx4 a = ((const floatx4*)in)[2 * i];
    floatx4 b = ((const floatx4*)in)[2 * i + 1];
#pragma unroll
    for (int e = 0; e < 4; ++e) { o[e] = (_Float16)a[e]; o[e + 4] = (_Float16)b[e]; }
  }
  ((half8*)out)[i] = o;
}

// biases + mask (mask pre-scaled by 2*log2e for exp2-domain softmax)
__global__ void k_cvt3(const void* __restrict__ ba, const void* __restrict__ bp,
                       const void* __restrict__ mk, float* __restrict__ baF,
                       float* __restrict__ bpF, float* __restrict__ mask2,
                       const int* __restrict__ flag) {
  int f = *flag;
  int i = blockIdx.x * 256 + threadIdx.x;
  auto cv = [&](const void* p, int j) {
    return f ? bf16_to_f32(((const unsigned short*)p)[j]) : ((const float*)p)[j];
  };
  if (i < 3072) baF[i] = cv(ba, i);
  else if (i < 4096) bpF[i - 3072] = cv(bp, i - 3072);
  else mask2[i - 4096] = cv(mk, i - 4096) * (2.0f * LOG2E);
}

// out[n*K + k] = (fp16) in[k*N + n]; two weights in one launch
__global__ __launch_bounds__(256) void k_transpose2(
    const void* __restrict__ inA, _Float16* __restrict__ outA,
    const void* __restrict__ inB, _Float16* __restrict__ outB,
    const int* __restrict__ flag) {
  __shared__ float tile[32][33];
  int f = *flag;
  const void* in;
  _Float16* out;
  int N, bid;
  if (blockIdx.x < 3072) { in = inA; out = outA; N = 3072; bid = blockIdx.x; }
  else { in = inB; out = outB; N = 1024; bid = blockIdx.x - 3072; }
  const int K = 1024;
  int nb = N >> 5;
  int bx = bid % nb, by = bid / nb;
  int n0 = bx << 5, k0 = by << 5;
  int c = threadIdx.x & 31, r = threadIdx.x >> 5;
  const float* fin = (const float*)in;
  const unsigned short* uin = (const unsigned short*)in;
#pragma unroll
  for (int i = 0; i < 4; ++i) {
    int kk = r + i * 8;
    size_t idx = (size_t)(k0 + kk) * N + n0 + c;
    tile[kk][c] = f ? bf16_to_f32(uin[idx]) : fin[idx];
  }
  __syncthreads();
#pragma unroll
  for (int i = 0; i < 4; ++i) {
    int nn = r + i * 8;
    out[(size_t)(n0 + nn) * K + k0 + c] = (_Float16)tile[c][nn];
  }
}

// ---------------- GEMM: D[m][n] = sum_k A[m][k]*BT[n][k] + bias[m] ----------------
// 128x128 tile, BK=64 (32 MFMA / 16 b128-reads / 1 barrier-pair per iter).
// LDS staging XOR-chunk-swizzled: global chunk scn folded into the source
// address so global_load_lds stays lane-linear; fragment reads 2-way max.
// outKind 0: scatter qkv^T -> Qs(x0.125*log2e)/Ks [b,h,t,d], Vt [b,h,d,t]
// outKind 1: write out[t][feature] as fp32 or bf16 (per flag)
__global__ __launch_bounds__(256) void k_gemm(
    const _Float16* __restrict__ A, const _Float16* __restrict__ BT,
    const float* __restrict__ bias, void* __restrict__ D0,
    void* __restrict__ D1, void* __restrict__ D2,
    int M, int N, int K, int outKind, const int* __restrict__ flag) {
  __shared__ _Float16 As[128 * 64] __attribute__((aligned(16)));
  __shared__ _Float16 Bs[128 * 64] __attribute__((aligned(16)));
  const int tid = threadIdx.x;
  const int wave = tid >> 6, lane = tid & 63;
  const int ln = lane & 15, quad = lane >> 4;
  const int bm = blockIdx.y * 128, bn = blockIdx.x * 128;
  const int wm = (wave & 1) * 64, wn = (wave >> 1) * 64;

  // staging: slot idx = tid + i*256 -> row = idx>>3 = sr + i*32, lds chunk = tid&7.
  // slot holds GLOBAL chunk scn = (tid&7) ^ (sr&7)  (row&7 == sr&7 since 32%8==0)
  const int sr = tid >> 3, scn = (tid & 7) ^ (sr & 7);
  const _Float16* Ag = A + (size_t)(bm + sr) * K + scn * 8;
  const _Float16* Bg = BT + (size_t)(bn + sr) * K + scn * 8;

  floatx4 acc[4][4] = {};

  for (int kt = 0; kt < K; kt += 64) {
    __syncthreads();
#pragma unroll
    for (int i = 0; i < 4; ++i) {
      load16_lds(Ag + kt + (size_t)i * 32 * K, As + (wave * 64 + i * 256) * 8, lane);
      load16_lds(Bg + kt + (size_t)i * 32 * K, Bs + (wave * 64 + i * 256) * 8, lane);
    }
    __syncthreads();
    half8 af[4][2], bf[4][2];
#pragma unroll
    for (int i = 0; i < 4; ++i) {
      int r = wm + i * 16 + ln;
#pragma unroll
      for (int ks = 0; ks < 2; ++ks)
        af[i][ks] = *(const half8*)(As + r * 64 + ((quad + 4 * ks) ^ (r & 7)) * 8);
    }
#pragma unroll
    for (int j = 0; j < 4; ++j) {
      int r = wn + j * 16 + ln;
#pragma unroll
      for (int ks = 0; ks < 2; ++ks)
        bf[j][ks] = *(const half8*)(Bs + r * 64 + ((quad + 4 * ks) ^ (r & 7)) * 8);
    }
#pragma unroll
    for (int ks = 0; ks < 2; ++ks)
#pragma unroll
      for (int i = 0; i < 4; ++i)
#pragma unroll
        for (int j = 0; j < 4; ++j)
          acc[i][j] = __builtin_amdgcn_mfma_f32_16x16x32_f16(af[i][ks], bf[j][ks], acc[i][j], 0, 0, 0);
  }

  if (outKind == 0) {
    _Float16* Qs = (_Float16*)D0;
    _Float16* Ks = (_Float16*)D1;
    _Float16* Vt = (_Float16*)D2;
    const float qsc = 0.125f * LOG2E;  // 1/sqrt(64) and log2e folded into Q
#pragma unroll
    for (int i = 0; i < 4; ++i) {
      int rbase = bm + wm + i * 16 + quad * 4;  // qkv feature, 4-aligned
      int sect = rbase >> 10;                   // 0:Q 1:K 2:V (wave-uniform)
      int cfeat = rbase & 1023;
      int h = cfeat >> 6, hd = cfeat & 63;
      float bv[4];
#pragma unroll
      for (int r = 0; r < 4; ++r) bv[r] = bias[rbase + r];
#pragma unroll
      for (int j = 0; j < 4; ++j) {
        int col = bn + wn + j * 16 + ln;        // global token
        int b = col >> 11, t = col & 2047;
        size_t bh = (size_t)b * N_HEADS + h;
        float v[4];
#pragma unroll
        for (int r = 0; r < 4; ++r) v[r] = acc[i][j][r] + bv[r];
        if (sect == 0) {
          half4 q;
#pragma unroll
          for (int r = 0; r < 4; ++r) q[r] = (_Float16)(v[r] * qsc);
          *(half4*)(Qs + (bh * T_SEQ + t) * 64 + hd) = q;
        } else if (sect == 1) {
          half4 kk4;
#pragma unroll
          for (int r = 0; r < 4; ++r) kk4[r] = (_Float16)v[r];
          *(half4*)(Ks + (bh * T_SEQ + t) * 64 + hd) = kk4;
        } else {
#pragma unroll
          for (int r = 0; r < 4; ++r)
            Vt[(bh * 64 + hd + r) * T_SEQ + t] = (_Float16)v[r];
        }
      }
    }
  } else {
    int mode = (*flag) ? 2 : 1;  // 2: bf16 out, 1: fp32 out
#pragma unroll
    for (int i = 0; i < 4; ++i) {
      int rbase = bm + wm + i * 16 + quad * 4;
      float bv[4];
#pragma unroll
      for (int r = 0; r < 4; ++r) bv[r] = bias[rbase + r];
#pragma unroll
      for (int j = 0; j < 4; ++j) {
        int col = bn + wn + j * 16 + ln;
        float v[4];
#pragma unroll
        for (int r = 0; r < 4; ++r) v[r] = acc[i][j][r] + bv[r];
        if (mode == 1) {
          floatx4 o = {v[0], v[1], v[2], v[3]};
          *(floatx4*)((float*)D0 + (size_t)col * M + rbase) = o;
        } else {
          ushort4v o;
#pragma unroll
          for (int r = 0; r < 4; ++r) o[r] = f32_to_bf16(v[r]);
          *(ushort4v*)((unsigned short*)D0 + (size_t)col * M + rbase) = o;
        }
      }
    }
  }
}

// ---------------- flash attention (R6 version: 16x16, S^T, fixed-ref softmax) ----------------
__global__ __launch_bounds__(256) void k_flash(
    const _Float16* __restrict__ Qs, const _Float16* __restrict__ Ks,
    const _Float16* __restrict__ Vt, const float* __restrict__ mask2,
    _Float16* __restrict__ O) {
  __shared__ _Float16 Kl[2][64 * 64] __attribute__((aligned(16)));  // [key][d] swizzled
  __shared__ _Float16 Vl[2][64 * 64] __attribute__((aligned(16)));  // [d][key] swizzled
  __shared__ _Float16 Pl[4][16 * 64] __attribute__((aligned(16)));  // per-wave P[q][key] swizzled
  const int tid = threadIdx.x, wave = tid >> 6, lane = tid & 63;
  const int ln = lane & 15, quad = lane >> 4;
  const int id = blockIdx.x;
  const int qc = id & 31, h = (id >> 5) & 15, b = id >> 9;
  const size_t bh = (size_t)b * N_HEADS + h;
  const _Float16* Qb = Qs + bh * T_SEQ * 64;
  const _Float16* Kb = Ks + bh * T_SEQ * 64;
  const _Float16* Vb = Vt + bh * 64 * T_SEQ;
  const int q0 = qc * 64 + wave * 16;

  half8 qf[2];
#pragma unroll
  for (int kk = 0; kk < 2; ++kk)
    qf[kk] = *(const half8*)(Qb + (size_t)(q0 + ln) * 64 + kk * 32 + quad * 8);

  floatx4 Oacc[4] = {};                 // O^T: d = jd*16+quad*4+r, q = ln
  float m0 = 0.f, l_i = 0.f;

  // staging pointers, advanced by constants each tile
  const int sr = tid >> 3, scn = (tid & 7) ^ (sr & 7);
  const _Float16* kp0 = Kb + (size_t)sr * 64 + scn * 8;
  const _Float16* kp1 = kp0 + 32 * 64;
  const _Float16* vp0 = Vb + (size_t)sr * T_SEQ + scn * 8;
  const _Float16* vp1 = vp0 + 32 * T_SEQ;
  const float* mq = mask2 + (size_t)b * T_SEQ + quad * 4;  // key-indexed mask

  const int ksw0 = ((quad) ^ (ln & 7)) * 8;      // K/V read chunk, kk=0
  const int ksw1 = ((4 + quad) ^ (ln & 7)) * 8;  // kk=1
  _Float16* Pw = &Pl[wave][0];
  const int lnx = ln & 7;

  // prime buffer 0
  {
    _Float16* K0 = &Kl[0][0] + (size_t)wave * 512;
    _Float16* V0 = &Vl[0][0] + (size_t)wave * 512;
    load16_lds(kp0, K0, lane);
    load16_lds(kp1, K0 + 2048, lane);
    load16_lds(vp0, V0, lane);
    load16_lds(vp1, V0 + 2048, lane);
    kp0 += 64 * 64; kp1 += 64 * 64; vp0 += 64; vp1 += 64;
  }

  for (int t = 0; t < 32; ++t) {
    const int cur = t & 1;
    __syncthreads();
    if (t + 1 < 32) {
      _Float16* K0 = &Kl[cur ^ 1][0] + (size_t)wave * 512;
      _Float16* V0 = &Vl[cur ^ 1][0] + (size_t)wave * 512;
      load16_lds(kp0, K0, lane);
      load16_lds(kp1, K0 + 2048, lane);
      load16_lds(vp0, V0, lane);
      load16_lds(vp1, V0 + 2048, lane);
      kp0 += 64 * 64; kp1 += 64 * 64; vp0 += 64; vp1 += 64;
    }
    const _Float16* Kc = &Kl[cur][0];
    const _Float16* Vc = &Vl[cur][0];

    floatx4 s[4];
#pragma unroll
    for (int j = 0; j < 4; ++j) {
      floatx4 z = *(const floatx4*)(mq + j * 16);  // mask as MFMA C-init
      half8 kf0 = *(const half8*)(Kc + (j * 16 + ln) * 64 + ksw0);
      z = __builtin_amdgcn_mfma_f32_16x16x32_f16(kf0, qf[0], z, 0, 0, 0);
      half8 kf1 = *(const half8*)(Kc + (j * 16 + ln) * 64 + ksw1);
      z = __builtin_amdgcn_mfma_f32_16x16x32_f16(kf1, qf[1], z, 0, 0, 0);
      s[j] = z;
    }
    mq += 64;

    if (t == 0) {
      // fixed per-query reference point from tile 0 (uniform across quads)
      float tmax = -__builtin_inff();
#pragma unroll
      for (int j = 0; j < 4; ++j)
#pragma unroll
        for (int r = 0; r < 4; ++r) tmax = fmaxf(tmax, s[j][r]);
      tmax = fmaxf(tmax, __shfl_xor(tmax, 16, 64));
      tmax = fmaxf(tmax, __shfl_xor(tmax, 32, 64));
      m0 = fmaxf(tmax, -50.f);  // floor guards all-masked tile-0
    }

#pragma unroll
    for (int j = 0; j < 4; ++j)
#pragma unroll
      for (int r = 0; r < 4; ++r) {
        float p = __builtin_amdgcn_exp2f(s[j][r] - m0);
        s[j][r] = p;
        l_i += p;
      }

    // P[q=ln][key] -> packed b64 writes, XOR-swizzled 8-half chunks
#pragma unroll
    for (int j = 0; j < 4; ++j) {
      half2v p01 = pk_f16(s[j][0], s[j][1]);
      half2v p23 = pk_f16(s[j][2], s[j][3]);
      half4 pk = {p01[0], p01[1], p23[0], p23[1]};
      int c = j * 2 + (quad >> 1);               // logical 8-half chunk
      *(half4*)(Pw + ln * 64 + (c ^ lnx) * 8 + (quad & 1) * 4) = pk;
    }
    // compiler-only ordering: DS pipe executes a wave's LDS ops in order,
    // so the read-back below needs no HW lgkmcnt(0) drain.
    asm volatile("" ::: "memory");
#pragma unroll
    for (int kk = 0; kk < 2; ++kk) {
      half8 pf = *(const half8*)(Pw + ln * 64 + ((kk * 4 + quad) ^ lnx) * 8);
      int ks = kk ? ksw1 : ksw0;
#pragma unroll
      for (int jd = 0; jd < 4; ++jd) {
        half8 vf = *(const half8*)(Vc + (jd * 16 + ln) * 64 + ks);
        Oacc[jd] = __builtin_amdgcn_mfma_f32_16x16x32_f16(vf, pf, Oacc[jd], 0, 0, 0);
      }
    }
  }

  // deferred cross-quad l reduction (quads hold disjoint keys of query ln)
  l_i += __shfl_xor(l_i, 16, 64);
  l_i += __shfl_xor(l_i, 32, 64);
  float inv = 1.f / l_i;
#pragma unroll
  for (int jd = 0; jd < 4; ++jd) {
    half4 ov;
#pragma unroll
    for (int r = 0; r < 4; ++r) ov[r] = (_Float16)(Oacc[jd][r] * inv);
    *(half4*)(O + ((size_t)b * T_SEQ + q0 + ln) * D_MODEL + h * 64 + jd * 16 + quad * 4) = ov;
  }
}

extern "C" void kernel_launch(void* const* d_in, const int* in_sizes, int n_in,
                              void* d_out, int out_size, void* d_ws, size_t ws_size,
                              hipStream_t stream) {
  const void* x      = d_in[0];
  const void* amask  = d_in[1];
  const void* w_attn = d_in[2];
  const void* b_attn = d_in[3];
  const void* w_proj = d_in[4];
  const void* b_proj = d_in[5];

  char* ws = (char*)d_ws;
  size_t off = 0;
  auto alloc = [&](size_t bytes) {
    void* p = ws + off;
    off += (bytes + 255) & ~(size_t)255;
    return p;
  };
  int* flag        = (int*)alloc(256);
  _Float16* Xh     = (_Float16*)alloc((size_t)4096 * 1024 * 2);
  _Float16* WaT    = (_Float16*)alloc((size_t)3072 * 1024 * 2);
  _Float16* WpT    = (_Float16*)alloc((size_t)1024 * 1024 * 2);
  float* baF       = (float*)alloc(3072 * 4);
  float* bpF       = (float*)alloc(1024 * 4);
  float* mask2     = (float*)alloc(4096 * 4);
  _Float16* Qs     = (_Float16*)alloc((size_t)4096 * 1024 * 2);
  _Float16* Ks     = (_Float16*)alloc((size_t)4096 * 1024 * 2);
  _Float16* Vt     = (_Float16*)alloc((size_t)4096 * 1024 * 2);
  _Float16* AttnH  = (_Float16*)alloc((size_t)4096 * 1024 * 2);

  k_detect<<<1, 256, 0, stream>>>((const unsigned short*)x, flag);
  k_cvt_h8<<<(4096 * 1024 / 8) / 256, 256, 0, stream>>>(x, Xh, 4096 * 1024 / 8, flag);
  k_transpose2<<<3072 + 1024, 256, 0, stream>>>(w_attn, WaT, w_proj, WpT, flag);
  k_cvt3<<<32, 256, 0, stream>>>(b_attn, b_proj, amask, baF, bpF, mask2, flag);

  // GEMM1: qkv^T = WaT(3072xK) . Xh(4096xK)^T, fused scatter to Qs/Ks/Vt
  dim3 g1(4096 / 128, 3072 / 128);
  k_gemm<<<g1, 256, 0, stream>>>(WaT, Xh, baF, Qs, Ks, Vt, 3072, 4096, 1024, 0, flag);

  k_flash<<<1024, 256, 0, stream>>>(Qs, Ks, Vt, mask2, AttnH);

  // GEMM2: out^T = WpT(1024xK) . AttnH(4096xK)^T -> d_out [t][1024]
  dim3 g2(4096 / 128, 1024 / 128);
  k_gemm<<<g2, 256, 0, stream>>>(WpT, AttnH, bpF, d_out, nullptr, nullptr, 1024, 4096, 1024, 1, flag);
}

// Round 9
// 208.463 us; speedup vs baseline: 1.1184x; 1.0602x over previous
//
#include <hip/hip_runtime.h>
#include <hip/hip_bf16.h>

#define T_SEQ 2048
#define D_MODEL 1024
#define N_HEADS 16

typedef _Float16 half8 __attribute__((ext_vector_type(8)));
typedef _Float16 half4 __attribute__((ext_vector_type(4)));
typedef _Float16 half2v __attribute__((ext_vector_type(2)));
typedef float floatx4 __attribute__((ext_vector_type(4)));
typedef unsigned short ushort4v __attribute__((ext_vector_type(4)));
typedef unsigned short ushort8v __attribute__((ext_vector_type(8)));

#define LOG2E 1.44269504088896f

__device__ __forceinline__ unsigned short f32_to_bf16(float f) {
  unsigned u = __builtin_bit_cast(unsigned, f);
  u = u + 0x7FFFu + ((u >> 16) & 1u);
  return (unsigned short)(u >> 16);
}
__device__ __forceinline__ float bf16_to_f32(unsigned short h) {
  unsigned u = ((unsigned)h) << 16;
  return __builtin_bit_cast(float, u);
}
__device__ __forceinline__ half2v pk_f16(float a, float b) {
  return __builtin_bit_cast(half2v, __builtin_amdgcn_cvt_pkrtz(a, b));
}

// async 16B/lane global->LDS. lds base must be wave-uniform; HW adds lane*16.
__device__ __forceinline__ void load16_lds(const _Float16* g, _Float16* lds_base, int lane) {
#if __has_builtin(__builtin_amdgcn_global_load_lds)
  __builtin_amdgcn_global_load_lds(
      (const __attribute__((address_space(1))) void*)g,
      (__attribute__((address_space(3))) void*)lds_base, 16, 0, 0);
#else
  *(half8*)(lds_base + lane * 8) = *(const half8*)g;
#endif
}

// ---------------- dtype detection (bf16 vs fp32 inputs) ----------------
__global__ void k_detect(const unsigned short* __restrict__ x, int* __restrict__ flag) {
  __shared__ int cnt;
  if (threadIdx.x == 0) cnt = 0;
  __syncthreads();
  unsigned short v = x[(size_t)threadIdx.x * 2];
  int e = (v >> 7) & 0xFF;
  int ok = (v == 0) || (e >= 100 && e <= 150);
  atomicAdd(&cnt, ok);
  __syncthreads();
  if (threadIdx.x == 0) *flag = (cnt >= 192) ? 1 : 0;  // 1 = bf16 inputs
}

// ---------------- conversions ----------------
// 8 elements/thread, vectorized both paths
__global__ void k_cvt_h8(const void* __restrict__ in, _Float16* __restrict__ out,
                         int n8, const int* __restrict__ flag) {
  int f = *flag;
  int i = blockIdx.x * 256 + threadIdx.x;
  if (i >= n8) return;
  half8 o;
  if (f) {
    ushort8v u = ((const ushort8v*)in)[i];
#pragma unroll
    for (int e = 0; e < 8; ++e) o[e] = (_Float16)bf16_to_f32(u[e]);
  } else {
    floatx4 a = ((const floatx4*)in)[2 * i];
    floatx4 b = ((const floatx4*)in)[2 * i + 1];
#pragma unroll
    for (int e = 0; e < 4; ++e) { o[e] = (_Float16)a[e]; o[e + 4] = (_Float16)b[e]; }
  }
  ((half8*)out)[i] = o;
}

// biases + mask (mask pre-scaled by 2*log2e for exp2-domain softmax)
__global__ void k_cvt3(const void* __restrict__ ba, const void* __restrict__ bp,
                       const void* __restrict__ mk, float* __restrict__ baF,
                       float* __restrict__ bpF, float* __restrict__ mask2,
                       const int* __restrict__ flag) {
  int f = *flag;
  int i = blockIdx.x * 256 + threadIdx.x;
  auto cv = [&](const void* p, int j) {
    return f ? bf16_to_f32(((const unsigned short*)p)[j]) : ((const float*)p)[j];
  };
  if (i < 3072) baF[i] = cv(ba, i);
  else if (i < 4096) bpF[i - 3072] = cv(bp, i - 3072);
  else mask2[i - 4096] = cv(mk, i - 4096) * (2.0f * LOG2E);
}

// out[n*K + k] = (fp16) in[k*N + n]; two weights in one launch
__global__ __launch_bounds__(256) void k_transpose2(
    const void* __restrict__ inA, _Float16* __restrict__ outA,
    const void* __restrict__ inB, _Float16* __restrict__ outB,
    const int* __restrict__ flag) {
  __shared__ float tile[32][33];
  int f = *flag;
  const void* in;
  _Float16* out;
  int N, bid;
  if (blockIdx.x < 3072) { in = inA; out = outA; N = 3072; bid = blockIdx.x; }
  else { in = inB; out = outB; N = 1024; bid = blockIdx.x - 3072; }
  const int K = 1024;
  int nb = N >> 5;
  int bx = bid % nb, by = bid / nb;
  int n0 = bx << 5, k0 = by << 5;
  int c = threadIdx.x & 31, r = threadIdx.x >> 5;
  const float* fin = (const float*)in;
  const unsigned short* uin = (const unsigned short*)in;
#pragma unroll
  for (int i = 0; i < 4; ++i) {
    int kk = r + i * 8;
    size_t idx = (size_t)(k0 + kk) * N + n0 + c;
    tile[kk][c] = f ? bf16_to_f32(uin[idx]) : fin[idx];
  }
  __syncthreads();
#pragma unroll
  for (int i = 0; i < 4; ++i) {
    int nn = r + i * 8;
    out[(size_t)(n0 + nn) * K + k0 + c] = (_Float16)tile[c][nn];
  }
}

// ---------------- GEMM: D[m][n] = sum_k A[m][k]*BT[n][k] + bias[m] ----------------
// 128x128 tile, BK=64; LDS staging XOR-chunk-swizzled (R8 version, unchanged).
__global__ __launch_bounds__(256) void k_gemm(
    const _Float16* __restrict__ A, const _Float16* __restrict__ BT,
    const float* __restrict__ bias, void* __restrict__ D0,
    void* __restrict__ D1, void* __restrict__ D2,
    int M, int N, int K, int outKind, const int* __restrict__ flag) {
  __shared__ _Float16 As[128 * 64] __attribute__((aligned(16)));
  __shared__ _Float16 Bs[128 * 64] __attribute__((aligned(16)));
  const int tid = threadIdx.x;
  const int wave = tid >> 6, lane = tid & 63;
  const int ln = lane & 15, quad = lane >> 4;
  const int bm = blockIdx.y * 128, bn = blockIdx.x * 128;
  const int wm = (wave & 1) * 64, wn = (wave >> 1) * 64;

  const int sr = tid >> 3, scn = (tid & 7) ^ (sr & 7);
  const _Float16* Ag = A + (size_t)(bm + sr) * K + scn * 8;
  const _Float16* Bg = BT + (size_t)(bn + sr) * K + scn * 8;

  floatx4 acc[4][4] = {};

  for (int kt = 0; kt < K; kt += 64) {
    __syncthreads();
#pragma unroll
    for (int i = 0; i < 4; ++i) {
      load16_lds(Ag + kt + (size_t)i * 32 * K, As + (wave * 64 + i * 256) * 8, lane);
      load16_lds(Bg + kt + (size_t)i * 32 * K, Bs + (wave * 64 + i * 256) * 8, lane);
    }
    __syncthreads();
    half8 af[4][2], bf[4][2];
#pragma unroll
    for (int i = 0; i < 4; ++i) {
      int r = wm + i * 16 + ln;
#pragma unroll
      for (int ks = 0; ks < 2; ++ks)
        af[i][ks] = *(const half8*)(As + r * 64 + ((quad + 4 * ks) ^ (r & 7)) * 8);
    }
#pragma unroll
    for (int j = 0; j < 4; ++j) {
      int r = wn + j * 16 + ln;
#pragma unroll
      for (int ks = 0; ks < 2; ++ks)
        bf[j][ks] = *(const half8*)(Bs + r * 64 + ((quad + 4 * ks) ^ (r & 7)) * 8);
    }
#pragma unroll
    for (int ks = 0; ks < 2; ++ks)
#pragma unroll
      for (int i = 0; i < 4; ++i)
#pragma unroll
        for (int j = 0; j < 4; ++j)
          acc[i][j] = __builtin_amdgcn_mfma_f32_16x16x32_f16(af[i][ks], bf[j][ks], acc[i][j], 0, 0, 0);
  }

  if (outKind == 0) {
    _Float16* Qs = (_Float16*)D0;
    _Float16* Ks = (_Float16*)D1;
    _Float16* Vt = (_Float16*)D2;
    const float qsc = 0.125f * LOG2E;  // 1/sqrt(64) and log2e folded into Q
#pragma unroll
    for (int i = 0; i < 4; ++i) {
      int rbase = bm + wm + i * 16 + quad * 4;
      int sect = rbase >> 10;
      int cfeat = rbase & 1023;
      int h = cfeat >> 6, hd = cfeat & 63;
      float bv[4];
#pragma unroll
      for (int r = 0; r < 4; ++r) bv[r] = bias[rbase + r];
#pragma unroll
      for (int j = 0; j < 4; ++j) {
        int col = bn + wn + j * 16 + ln;
        int b = col >> 11, t = col & 2047;
        size_t bh = (size_t)b * N_HEADS + h;
        float v[4];
#pragma unroll
        for (int r = 0; r < 4; ++r) v[r] = acc[i][j][r] + bv[r];
        if (sect == 0) {
          half4 q;
#pragma unroll
          for (int r = 0; r < 4; ++r) q[r] = (_Float16)(v[r] * qsc);
          *(half4*)(Qs + (bh * T_SEQ + t) * 64 + hd) = q;
        } else if (sect == 1) {
          half4 kk4;
#pragma unroll
          for (int r = 0; r < 4; ++r) kk4[r] = (_Float16)v[r];
          *(half4*)(Ks + (bh * T_SEQ + t) * 64 + hd) = kk4;
        } else {
#pragma unroll
          for (int r = 0; r < 4; ++r)
            Vt[(bh * 64 + hd + r) * T_SEQ + t] = (_Float16)v[r];
        }
      }
    }
  } else {
    int mode = (*flag) ? 2 : 1;  // 2: bf16 out, 1: fp32 out
#pragma unroll
    for (int i = 0; i < 4; ++i) {
      int rbase = bm + wm + i * 16 + quad * 4;
      float bv[4];
#pragma unroll
      for (int r = 0; r < 4; ++r) bv[r] = bias[rbase + r];
#pragma unroll
      for (int j = 0; j < 4; ++j) {
        int col = bn + wn + j * 16 + ln;
        float v[4];
#pragma unroll
        for (int r = 0; r < 4; ++r) v[r] = acc[i][j][r] + bv[r];
        if (mode == 1) {
          floatx4 o = {v[0], v[1], v[2], v[3]};
          *(floatx4*)((float*)D0 + (size_t)col * M + rbase) = o;
        } else {
          ushort4v o;
#pragma unroll
          for (int r = 0; r < 4; ++r) o[r] = f32_to_bf16(v[r]);
          *(ushort4v*)((unsigned short*)D0 + (size_t)col * M + rbase) = o;
        }
      }
    }
  }
}

// ---------------- flash attention v3: 2x2 wave split (query-half x key-half) ----------------
// block = (b, h, 64 queries), 4 waves: wave = (qh = w&1)*32 q x (kh = w>>1)*32 k
// quadrant per 64-key tile. Q in registers (fixed). Each wave accumulates a
// PARTIAL O over its key-half with its own fixed softmax reference m0 (tile-0
// max of its keys); one end-of-kernel cross-wave merge (kh=1 dumps O/m0/l to
// LDS overlaid on dead K/V buffers; kh=0 rescale-merges by 2^(m0-M), writes).
// Cuts per-tile LDS traffic 96->64 KB/block (K/V frag redundancy 4x -> 2x).
__global__ __launch_bounds__(256, 4) void k_flash(
    const _Float16* __restrict__ Qs, const _Float16* __restrict__ Ks,
    const _Float16* __restrict__ Vt, const float* __restrict__ mask2,
    _Float16* __restrict__ O) {
  __shared__ __attribute__((aligned(16))) char smem[40960];
  _Float16* KlB = (_Float16*)smem;             // [2][64*64] dbuf, swizzled
  _Float16* VlB = (_Float16*)(smem + 16384);   // [2][64*64] dbuf, swizzled
  _Float16* PlB = (_Float16*)(smem + 32768);   // [4][32*32] per-wave P
  float* Red = (float*)smem;                   // [2][64][36] overlay (post-loop)

  const int tid = threadIdx.x, wave = tid >> 6, lane = tid & 63;
  const int ln = lane & 15, quad = lane >> 4;
  const int qh = wave & 1, kh = wave >> 1;
  const int id = blockIdx.x;
  const int qc = id & 31, h = (id >> 5) & 15, b = id >> 9;
  const size_t bh = (size_t)b * N_HEADS + h;
  const _Float16* Qb = Qs + bh * T_SEQ * 64;
  const _Float16* Kb = Ks + bh * T_SEQ * 64;
  const _Float16* Vb = Vt + bh * 64 * T_SEQ;
  const int q0w = qc * 64 + qh * 32;  // wave's 32-query base

  // Q B-frags (fixed): qf[jq][kk] = Q[q0w + jq*16 + ln][kk*32 + quad*8 + e]
  half8 qf[2][2];
#pragma unroll
  for (int jq = 0; jq < 2; ++jq)
#pragma unroll
    for (int kk = 0; kk < 2; ++kk)
      qf[jq][kk] = *(const half8*)(Qb + (size_t)(q0w + jq * 16 + ln) * 64 + kk * 32 + quad * 8);

  floatx4 Oacc[4][2] = {};        // [jd d-group][jq]: O^T partial (wave's keys)
  float m0[2] = {0.f, 0.f}, li[2] = {0.f, 0.f};

  // staging (all 4 waves cooperate, unchanged from R8)
  const int sr = tid >> 3, scn = (tid & 7) ^ (sr & 7);
  const _Float16* kp0 = Kb + (size_t)sr * 64 + scn * 8;
  const _Float16* kp1 = kp0 + 32 * 64;
  const _Float16* vp0 = Vb + (size_t)sr * T_SEQ + scn * 8;
  const _Float16* vp1 = vp0 + 32 * T_SEQ;
  const float* mqw = mask2 + (size_t)b * T_SEQ + kh * 32 + quad * 4;  // key-indexed

  _Float16* Pw = PlB + wave * 1024;

  // prime buffer 0
  {
    _Float16* K0 = KlB + (size_t)wave * 512;
    _Float16* V0 = VlB + (size_t)wave * 512;
    load16_lds(kp0, K0, lane);
    load16_lds(kp1, K0 + 2048, lane);
    load16_lds(vp0, V0, lane);
    load16_lds(vp1, V0 + 2048, lane);
    kp0 += 64 * 64; kp1 += 64 * 64; vp0 += 64; vp1 += 64;
  }

  for (int t = 0; t < 32; ++t) {
    const int cur = t & 1;
    __syncthreads();
    if (t + 1 < 32) {
      _Float16* K0 = KlB + (cur ^ 1) * 4096 + (size_t)wave * 512;
      _Float16* V0 = VlB + (cur ^ 1) * 4096 + (size_t)wave * 512;
      load16_lds(kp0, K0, lane);
      load16_lds(kp1, K0 + 2048, lane);
      load16_lds(vp0, V0, lane);
      load16_lds(vp1, V0 + 2048, lane);
      kp0 += 64 * 64; kp1 += 64 * 64; vp0 += 64; vp1 += 64;
    }
    const _Float16* Kc = KlB + cur * 4096;
    const _Float16* Vc = VlB + cur * 4096;

    // S quadrant: s[jk][jq], keys = kh*32 + jk*16 + (quad*4 + r), q = jq*16+ln
    floatx4 s[2][2];
#pragma unroll
    for (int jk = 0; jk < 2; ++jk) {
      const int krow = kh * 32 + jk * 16 + ln;
      half8 kf0 = *(const half8*)(Kc + krow * 64 + ((quad) ^ (krow & 7)) * 8);
      half8 kf1 = *(const half8*)(Kc + krow * 64 + ((4 + quad) ^ (krow & 7)) * 8);
#pragma unroll
      for (int jq = 0; jq < 2; ++jq) {
        floatx4 z = *(const floatx4*)(mqw + jk * 16);  // mask as MFMA C-init
        z = __builtin_amdgcn_mfma_f32_16x16x32_f16(kf0, qf[jq][0], z, 0, 0, 0);
        z = __builtin_amdgcn_mfma_f32_16x16x32_f16(kf1, qf[jq][1], z, 0, 0, 0);
        s[jk][jq] = z;
      }
    }
    mqw += 64;

    if (t == 0) {
      // fixed per-query reference from tile-0 keys of THIS wave's key-half
#pragma unroll
      for (int jq = 0; jq < 2; ++jq) {
        float tm = -__builtin_inff();
#pragma unroll
        for (int jk = 0; jk < 2; ++jk)
#pragma unroll
          for (int r = 0; r < 4; ++r) tm = fmaxf(tm, s[jk][jq][r]);
        tm = fmaxf(tm, __shfl_xor(tm, 16, 64));
        tm = fmaxf(tm, __shfl_xor(tm, 32, 64));
        m0[jq] = fmaxf(tm, -50.f);
      }
    }

#pragma unroll
    for (int jk = 0; jk < 2; ++jk)
#pragma unroll
      for (int jq = 0; jq < 2; ++jq)
#pragma unroll
        for (int r = 0; r < 4; ++r) {
          float p = __builtin_amdgcn_exp2f(s[jk][jq][r] - m0[jq]);
          s[jk][jq][r] = p;
          li[jq] += p;
        }

    // P[q row][key col] per wave: 32x32 fp16, 4-chunk rows, XOR(row&3) swizzle
#pragma unroll
    for (int jk = 0; jk < 2; ++jk)
#pragma unroll
      for (int jq = 0; jq < 2; ++jq) {
        half2v p01 = pk_f16(s[jk][jq][0], s[jk][jq][1]);
        half2v p23 = pk_f16(s[jk][jq][2], s[jk][jq][3]);
        half4 pk = {p01[0], p01[1], p23[0], p23[1]};
        int row = jq * 16 + ln;
        int cw = (jk * 2 + (quad >> 1)) ^ (row & 3);
        *(half4*)(Pw + row * 32 + cw * 8 + (quad & 1) * 4) = pk;
      }
    asm volatile("" ::: "memory");
    half8 pf[2];
#pragma unroll
    for (int jq = 0; jq < 2; ++jq) {
      int row = jq * 16 + ln;
      pf[jq] = *(const half8*)(Pw + row * 32 + (quad ^ (row & 3)) * 8);
    }
#pragma unroll
    for (int jd = 0; jd < 4; ++jd) {
      const int vrow = jd * 16 + ln;
      half8 vf = *(const half8*)(Vc + vrow * 64 + ((kh * 4 + quad) ^ (vrow & 7)) * 8);
#pragma unroll
      for (int jq = 0; jq < 2; ++jq)
        Oacc[jd][jq] = __builtin_amdgcn_mfma_f32_16x16x32_f16(vf, pf[jq], Oacc[jd][jq], 0, 0, 0);
    }
  }

  // finish per-wave l (sum across quads = key rows)
#pragma unroll
  for (int jq = 0; jq < 2; ++jq) {
    li[jq] += __shfl_xor(li[jq], 16, 64);
    li[jq] += __shfl_xor(li[jq], 32, 64);
  }

  // cross-wave merge: kh=1 dumps partials to LDS; kh=0 merges and writes
  __syncthreads();
  float* myRed = Red + ((size_t)qh * 64 + lane) * 36;
  if (kh) {
#pragma unroll
    for (int jd = 0; jd < 4; ++jd)
#pragma unroll
      for (int jq = 0; jq < 2; ++jq)
#pragma unroll
        for (int r = 0; r < 4; ++r) myRed[jd * 8 + jq * 4 + r] = Oacc[jd][jq][r];
#pragma unroll
    for (int jq = 0; jq < 2; ++jq) {
      myRed[32 + jq] = m0[jq];
      myRed[34 + jq] = li[jq];
    }
  }
  __syncthreads();
  if (!kh) {
    float sa[2], sb[2], inv[2];
#pragma unroll
    for (int jq = 0; jq < 2; ++jq) {
      float Mb = myRed[32 + jq], lb = myRed[34 + jq];
      float M = fmaxf(m0[jq], Mb);
      sa[jq] = __builtin_amdgcn_exp2f(m0[jq] - M);
      sb[jq] = __builtin_amdgcn_exp2f(Mb - M);
      inv[jq] = 1.f / (li[jq] * sa[jq] + lb * sb[jq]);
    }
#pragma unroll
    for (int jd = 0; jd < 4; ++jd)
#pragma unroll
      for (int jq = 0; jq < 2; ++jq) {
        half4 ov;
#pragma unroll
        for (int r = 0; r < 4; ++r) {
          float v = Oacc[jd][jq][r] * sa[jq] + myRed[jd * 8 + jq * 4 + r] * sb[jq];
          ov[r] = (_Float16)(v * inv[jq]);
        }
        *(half4*)(O + ((size_t)b * T_SEQ + q0w + jq * 16 + ln) * D_MODEL +
                  h * 64 + jd * 16 + quad * 4) = ov;
      }
  }
}

extern "C" void kernel_launch(void* const* d_in, const int* in_sizes, int n_in,
                              void* d_out, int out_size, void* d_ws, size_t ws_size,
                              hipStream_t stream) {
  const void* x      = d_in[0];
  const void* amask  = d_in[1];
  const void* w_attn = d_in[2];
  const void* b_attn = d_in[3];
  const void* w_proj = d_in[4];
  const void* b_proj = d_in[5];

  char* ws = (char*)d_ws;
  size_t off = 0;
  auto alloc = [&](size_t bytes) {
    void* p = ws + off;
    off += (bytes + 255) & ~(size_t)255;
    return p;
  };
  int* flag        = (int*)alloc(256);
  _Float16* Xh     = (_Float16*)alloc((size_t)4096 * 1024 * 2);
  _Float16* WaT    = (_Float16*)alloc((size_t)3072 * 1024 * 2);
  _Float16* WpT    = (_Float16*)alloc((size_t)1024 * 1024 * 2);
  float* baF       = (float*)alloc(3072 * 4);
  float* bpF       = (float*)alloc(1024 * 4);
  float* mask2     = (float*)alloc(4096 * 4);
  _Float16* Qs     = (_Float16*)alloc((size_t)4096 * 1024 * 2);
  _Float16* Ks     = (_Float16*)alloc((size_t)4096 * 1024 * 2);
  _Float16* Vt     = (_Float16*)alloc((size_t)4096 * 1024 * 2);
  _Float16* AttnH  = (_Float16*)alloc((size_t)4096 * 1024 * 2);

  k_detect<<<1, 256, 0, stream>>>((const unsigned short*)x, flag);
  k_cvt_h8<<<(4096 * 1024 / 8) / 256, 256, 0, stream>>>(x, Xh, 4096 * 1024 / 8, flag);
  k_transpose2<<<3072 + 1024, 256, 0, stream>>>(w_attn, WaT, w_proj, WpT, flag);
  k_cvt3<<<32, 256, 0, stream>>>(b_attn, b_proj, amask, baF, bpF, mask2, flag);

  // GEMM1: qkv^T = WaT(3072xK) . Xh(4096xK)^T, fused scatter to Qs/Ks/Vt
  dim3 g1(4096 / 128, 3072 / 128);
  k_gemm<<<g1, 256, 0, stream>>>(WaT, Xh, baF, Qs, Ks, Vt, 3072, 4096, 1024, 0, flag);

  k_flash<<<1024, 256, 0, stream>>>(Qs, Ks, Vt, mask2, AttnH);

  // GEMM2: out^T = WpT(1024xK) . AttnH(4096xK)^T -> d_out [t][1024]
  dim3 g2(4096 / 128, 1024 / 128);
  k_gemm<<<g2, 256, 0, stream>>>(WpT, AttnH, bpF, d_out, nullptr, nullptr, 1024, 4096, 1024, 1, flag);
}